// Round 12
// baseline (391.941 us; speedup 1.0000x reference)
//
#include <hip/hip_runtime.h>
#include <math.h>

typedef __bf16 bf16;
typedef __bf16 bf16x4 __attribute__((ext_vector_type(4)));
typedef __bf16 bf16x8 __attribute__((ext_vector_type(8)));
typedef _Float16 f16;
typedef _Float16 f16x4 __attribute__((ext_vector_type(4)));
typedef _Float16 f16x8 __attribute__((ext_vector_type(8)));
typedef float floatx4 __attribute__((ext_vector_type(4)));
typedef float floatx16 __attribute__((ext_vector_type(16)));
typedef short shortx4 __attribute__((ext_vector_type(4)));

#define MFMA_BF16(a, b, c) __builtin_amdgcn_mfma_f32_16x16x32_bf16((a), (b), (c), 0, 0, 0)
#define MFMA_F16(a, b, c) __builtin_amdgcn_mfma_f32_16x16x32_f16((a), (b), (c), 0, 0, 0)
#define MFMA32_BF16(a, b, c) __builtin_amdgcn_mfma_f32_32x32x16_bf16((a), (b), (c), 0, 0, 0)

// PV matmul 32x32 with K=8 (hedged; zero-pad K=16 fallback is equivalent).
__device__ inline floatx16 MFMA_PV32(bf16x4 a, bf16x4 b, floatx16 c) {
#if __has_builtin(__builtin_amdgcn_mfma_f32_32x32x8_bf16)
  return __builtin_amdgcn_mfma_f32_32x32x8_bf16(a, b, c, 0, 0, 0);
#elif __has_builtin(__builtin_amdgcn_mfma_f32_32x32x8bf16_1k)
  shortx4 as, bs;
  __builtin_memcpy(&as, &a, 8);
  __builtin_memcpy(&bs, &b, 8);
  return __builtin_amdgcn_mfma_f32_32x32x8bf16_1k(as, bs, c, 0, 0, 0);
#else
  bf16 z = (bf16)0.f;
  bf16x8 a8 = {a[0], a[1], a[2], a[3], z, z, z, z};
  bf16x8 b8 = {b[0], b[1], b[2], b[3], z, z, z, z};
  return MFMA32_BF16(a8, b8, c);
#endif
}

__device__ inline float fast_exp2(float x) {
#if __has_builtin(__builtin_amdgcn_exp2f)
  return __builtin_amdgcn_exp2f(x);
#else
  return exp2f(x);
#endif
}

// Direct global->LDS DMA, 16 B per lane. LDS dest is wave-uniform base;
// HW writes lane i at ldst + i*16 (linear; no padding allowed).
__device__ inline void gload16(const void* g, void* l) {
  __builtin_amdgcn_global_load_lds(
      (const __attribute__((address_space(1))) void*)g,
      (__attribute__((address_space(3))) void*)l, 16, 0, 0);
}

// mask int64 (0/1 values): all odd uint32 words are 0. int32: OR is nonzero.
__device__ inline int detect_i64(const void* m_) {
  const unsigned int* m = (const unsigned int*)m_;
  unsigned int o = 0;
  for (int i = 1; i < 256; i += 2) o |= m[i];
  return o == 0;
}

// XCD-aware chunked remap (T1). Requires nwg % 8 == 0 (all our grids comply).
__device__ inline int xcd_swizzle(int bid, int nwg) {
  return (bid & 7) * (nwg >> 3) + (bid >> 3);
}

// ---------------------------------------------------------------------------
// Weights: fp32 [R][C] -> fp16, TRANSPOSED [C][R]. Run once.
// ---------------------------------------------------------------------------
__global__ void wsplit(const float* __restrict__ in, f16* __restrict__ out,
                       int R, int C) {
  __shared__ float tile[32][33];
  int bx = blockIdx.x * 32, by = blockIdx.y * 32;
  int tx = threadIdx.x, ty = threadIdx.y;
#pragma unroll
  for (int i = 0; i < 32; i += 8)
    tile[ty + i][tx] = in[(size_t)(by + ty + i) * C + bx + tx];
  __syncthreads();
#pragma unroll
  for (int i = 0; i < 32; i += 8) {
    float x = tile[tx][ty + i];
    size_t oi = (size_t)(bx + ty + i) * R + by + tx;
    out[oi] = (f16)x;
  }
}

// ---------------------------------------------------------------------------
// Activations: fp32 -> fp16, linear (R19). 16 elems/thread, coalesced.
// ---------------------------------------------------------------------------
__global__ __launch_bounds__(256) void hconv(const float* __restrict__ in,
                                             f16* __restrict__ out) {
  int idx = (blockIdx.x * 256 + threadIdx.x) * 16;
#pragma unroll
  for (int u = 0; u < 4; ++u) {
    floatx4 v = *(const floatx4*)&in[idx + u * 4];
    f16x4 h;
#pragma unroll
    for (int j = 0; j < 4; ++j) h[j] = (f16)v[j];
    *(f16x4*)&out[idx + u * 4] = h;
  }
}

// ---------------------------------------------------------------------------
// C = A[M,K] @ B[K,N] + bias, fp16 single-pass MFMA. R19: A is fp16 in
// global for BOTH modes (hs pre-converted by hconv) -> all staging is
// global_load_lds DMA; the MODE-1 fp32 reg round-trip (ISSUE/WRITE_A) is
// deleted. R12 structure: double-buffered LDS, stage-next-FIRST, ONE
// barrier per K-step; DMA tiles XOR-swizzled both-sides (rule #21).
// row_base: global row offset (QKV gemm runs in two M-halves; A rows are
// half-local, C rows global).
// ---------------------------------------------------------------------------
template <int MODE>
__global__ __launch_bounds__(256) void gemm(
    const f16* __restrict__ Av, const f16* __restrict__ Bg,
    const float* __restrict__ bias, void* __restrict__ Cq,
    bf16* __restrict__ Ck, bf16* __restrict__ Cv, int M, int N, int K,
    int row_base) {
  __shared__ __align__(16) f16 Ah[2][128][32];
  __shared__ __align__(16) f16 Bs[2][128][32];

  int tid = threadIdx.x;
  int wave = tid >> 6, lane = tid & 63;
  int quad = lane >> 4, c = lane & 15;
  int wrow = (wave >> 1) * 64, wcol = (wave & 1) * 64;

  int nwg = gridDim.x * gridDim.y;
  int bid = blockIdx.x + gridDim.x * blockIdx.y;
  int nb = xcd_swizzle(bid, nwg);
  int m0 = (nb / gridDim.x) * 128, n0 = (nb % gridDim.x) * 128;

  int srow = lane >> 2;
  int ql8 = (((lane & 3) ^ ((lane >> 3) & 3)) * 8);
  int rswz = (c >> 1) & 3;

  floatx4 zero4 = {0.f, 0.f, 0.f, 0.f};
  floatx4 acc[4][4];
#pragma unroll
  for (int i = 0; i < 4; ++i)
#pragma unroll
    for (int j = 0; j < 4; ++j) acc[i][j] = zero4;

#define STAGE_AB(buf, kk)                                                   \
  {                                                                         \
    _Pragma("unroll") for (int u = 0; u < 2; ++u) {                         \
      int ch = wave * 2 + u;                                                \
      size_t gb = (size_t)(n0 + ch * 16 + srow) * K + (kk) + ql8;           \
      gload16(&Bg[gb], &Bs[buf][ch * 16][0]);                               \
      size_t ga = (size_t)(m0 + ch * 16 + srow) * K + (kk) + ql8;           \
      gload16(&Av[ga], &Ah[buf][ch * 16][0]);                               \
    }                                                                       \
  }

  STAGE_AB(0, 0);
  __syncthreads();

  int nk = K / 32;
  int cur = 0;
  for (int t = 0; t < nk; ++t) {
    bool has_next = (t + 1 < nk);
    if (has_next) STAGE_AB(cur ^ 1, (t + 1) * 32);

    f16x8 ah[4], bh[4];
#pragma unroll
    for (int i = 0; i < 4; ++i)
      ah[i] = *(const f16x8*)&Ah[cur][wrow + i * 16 + c][(quad ^ rswz) * 8];
#pragma unroll
    for (int j = 0; j < 4; ++j)
      bh[j] = *(const f16x8*)&Bs[cur][wcol + j * 16 + c][(quad ^ rswz) * 8];
#pragma unroll
    for (int i = 0; i < 4; ++i)
#pragma unroll
      for (int j = 0; j < 4; ++j)
        acc[i][j] = MFMA_F16(ah[i], bh[j], acc[i][j]);

    if (has_next) {
      __syncthreads();
      cur ^= 1;
    }
  }
#undef STAGE_AB

  // epilogue: C/D layout col = lane&15, row = quad*4 + reg
#pragma unroll
  for (int i = 0; i < 4; ++i) {
#pragma unroll
    for (int j = 0; j < 4; ++j) {
      int col = n0 + wcol + j * 16 + c;
      float bvv = bias[col];
#pragma unroll
      for (int r = 0; r < 4; ++r) {
        int row = row_base + m0 + wrow + i * 16 + quad * 4 + r;
        float v = acc[i][j][r] + bvv;
        if constexpr (MODE == 0) {
          ((float*)Cq)[(size_t)row * N + col] = v;
        } else {
          int which = col >> 10;          // 0=Q,1=K,2=V (wave-uniform)
          int h = (col >> 6) & 15;
          int d = col & 63;
          int b = row >> 11;
          int s = row & 2047;
          if (which == 0) {
            ((bf16*)Cq)[((size_t)(b * 2048 + s)) * 1024 + h * 64 + d] = (bf16)v;
          } else if (which == 1) {
            Ck[((size_t)(b * 16 + h) * 2048 + s) * 64 + d] = (bf16)v;
          } else {
            Cv[((size_t)(b * 16 + h) * 64 + d) * 2048 + s] = (bf16)v;
          }
        }
      }
    }
  }
}

// ---------------------------------------------------------------------------
// Fused MFMA flash attention — EXACT R17 revert (143.6 µs verified): 32x32
// MFMA, 128-q blocks, reg-staged K/V ping-pong phases, in-register P (S^T
// C/D reg-group == K=8 PV B-frag). Only change vs benched R17: exp2 with
// log2e folded into the fmaf constants (arithmetic identity, saves a
// v_mul per exp). O stored fp16 for the fp16 proj GEMM.
// ---------------------------------------------------------------------------
__global__ __launch_bounds__(256) void attn_fused(
    bf16* QO, const bf16* __restrict__ Kg, const bf16* __restrict__ Vg,
    const void* __restrict__ mask) {
  __shared__ __align__(16) bf16 Ks[64][72];   // [key][d]
  __shared__ __align__(16) bf16 Vts[64][72];  // [d][key]
  __shared__ __align__(16) float abuf_all[2048];  // mv ? -12*log2e : -1e30

  const int i64 = detect_i64(mask);

  int tid = threadIdx.x;
  int wave = tid >> 6, lane = tid & 63;
  int l31 = lane & 31, hi = lane >> 5;

  // T1: XCD-chunked remap; consecutive new ids share bh -> K/V L2 reuse.
  int nwg = gridDim.x * gridDim.y;  // 1024
  int bid = blockIdx.x + gridDim.x * blockIdx.y;
  int nb = xcd_swizzle(bid, nwg);
  int qt = nb & 15, bh = nb >> 4;

  int b = bh >> 4, h = bh & 15;
  int q0 = qt * 128;
  bf16* Qp = QO + (size_t)b * 2048 * 1024 + h * 64;  // row stride 1024
  const bf16* Kp = Kg + (size_t)bh * 2048 * 64;      // [s][d]
  const bf16* Vp = Vg + (size_t)bh * 64 * 2048;      // [d][s] (transposed)

  // mask table for all 2048 keys of batch b (log2e units; once, read-only)
#pragma unroll
  for (int i = 0; i < 8; ++i) {
    int key = tid * 8 + i;
    int idx = b * 2048 + key;
    int mv = i64 ? (int)((const long long*)mask)[idx]
                 : ((const int*)mask)[idx];
    abuf_all[key] = mv ? -17.3123404907f : -1e30f;
  }

  // Q frags (B-operand of 32x32x16 QK^T): col q = l31, k = hi*8+i per dstep.
  int qrow = q0 + wave * 32 + l31;
  bf16x8 qf[4];
#pragma unroll
  for (int ds = 0; ds < 4; ++ds)
    qf[ds] = *(const bf16x8*)&Qp[(size_t)qrow * 1024 + ds * 16 + hi * 8];

  floatx16 o[2];
#pragma unroll
  for (int dt = 0; dt < 2; ++dt)
#pragma unroll
    for (int i = 0; i < 16; ++i) o[dt][i] = 0.f;
  float lacc = 0.f;

  // prologue: stage K_0
#pragma unroll
  for (int p = 0; p < 2; ++p) {
    int off = p * 2048 + tid * 8;
    int r = off >> 6, cc = off & 63;
    *(bf16x8*)&Ks[r][cc] = *(const bf16x8*)&Kp[(size_t)r * 64 + cc];
  }
  __syncthreads();  // Ks_0 + abuf_all visible

  bf16x4 pk[8];  // P^T frags: pk[t2*4+s] = keys t2*32 + 8s + 4hi + j

  for (int kt = 0; kt < 32; ++kt) {
    int k0 = kt * 64;

    // ---- phase A: issue V_t; QK^T both tiles; softmax->pk; write V_t ----
    bf16x8 vstage[2];
#pragma unroll
    for (int p = 0; p < 2; ++p) {
      int off = p * 2048 + tid * 8;
      int r = off >> 6, cc = off & 63;
      vstage[p] = *(const bf16x8*)&Vp[(size_t)r * 2048 + k0 + cc];
    }

#pragma unroll
    for (int t2 = 0; t2 < 2; ++t2) {
      floatx16 sr;
#pragma unroll
      for (int i = 0; i < 16; ++i) sr[i] = 0.f;
#pragma unroll
      for (int ds = 0; ds < 4; ++ds) {
        bf16x8 ak = *(const bf16x8*)&Ks[t2 * 32 + l31][ds * 16 + hi * 8];
        sr = MFMA32_BF16(ak, qf[ds], sr);
      }
      // softmax in-register; reg group 4s..4s+3 -> keys t2*32+8s+4hi+j
#pragma unroll
      for (int s = 0; s < 4; ++s) {
        floatx4 am = *(const floatx4*)&abuf_all[k0 + t2 * 32 + s * 8 + hi * 4];
        bf16x4 p4;
#pragma unroll
        for (int j = 0; j < 4; ++j) {
          // exp(x/8 - 12) == exp2(x*0.125*log2e - 12*log2e)
          float pv = fast_exp2(fmaf(sr[s * 4 + j], 0.1803368801f, am[j]));
          lacc += pv;
          p4[j] = (bf16)pv;
        }
        pk[t2 * 4 + s] = p4;
      }
    }

    // write V_t (vstage vmcnt hidden under QK^T/softmax)
#pragma unroll
    for (int p = 0; p < 2; ++p) {
      int off = p * 2048 + tid * 8;
      int r = off >> 6, cc = off & 63;
      *(bf16x8*)&Vts[r][cc] = vstage[p];
    }
    __syncthreads();  // V_t visible; Ks free for overwrite

    // ---- phase B: issue K_{t+1}; PV; write K_{t+1} ----
    bf16x8 kstage[2];
    bool more = (kt + 1) < 32;
    int kn = k0 + 64;
    if (more) {
#pragma unroll
      for (int p = 0; p < 2; ++p) {
        int off = p * 2048 + tid * 8;
        int r = off >> 6, cc = off & 63;
        kstage[p] = *(const bf16x8*)&Kp[(size_t)(kn + r) * 64 + cc];
      }
    }

    // O^T += V^T @ P^T: A = Vts[dt*32+l31][ss*8+hi*4] (b64), B = pk[ss]
#pragma unroll
    for (int ss = 0; ss < 8; ++ss) {
#pragma unroll
      for (int dt = 0; dt < 2; ++dt) {
        bf16x4 av = *(const bf16x4*)&Vts[dt * 32 + l31][ss * 8 + hi * 4];
        o[dt] = MFMA_PV32(av, pk[ss], o[dt]);
      }
    }

    if (more) {
#pragma unroll
      for (int p = 0; p < 2; ++p) {
        int off = p * 2048 + tid * 8;
        int r = off >> 6, cc = off & 63;
        *(bf16x8*)&Ks[r][cc] = kstage[p];
      }
      __syncthreads();  // K_{t+1} visible; Vts free
    }
  }

  // l(q) = own half (this hi's 32 keys/kt) + partner half
  lacc += __shfl_xor(lacc, 32, 64);
  float inv = 1.0f / fmaxf(lacc, 1e-30f);

  // O^T C/D: col q = l31, row d_local = (reg&3)+8*(reg>>2)+4*hi (+32*dt).
  // Store fp16, groups of 4 consecutive d.
#pragma unroll
  for (int dt = 0; dt < 2; ++dt) {
#pragma unroll
    for (int t = 0; t < 4; ++t) {
      f16x4 out;
#pragma unroll
      for (int j = 0; j < 4; ++j) out[j] = (f16)(o[dt][t * 4 + j] * inv);
      int d0 = dt * 32 + t * 8 + hi * 4;
      *(f16x4*)((f16*)&Qp[(size_t)qrow * 1024] + d0) = out;
    }
  }
}

// ---------------------------------------------------------------------------
extern "C" void kernel_launch(void* const* d_in, const int* in_sizes, int n_in,
                              void* d_out, int out_size, void* d_ws, size_t ws_size,
                              hipStream_t stream) {
  (void)in_sizes; (void)n_in; (void)out_size;
  const float* hs    = (const float*)d_in[0];  // [4,2048,1024] fp32
  const float* qkv_w = (const float*)d_in[1];  // [1024,3072] fp32
  const float* qkv_b = (const float*)d_in[2];  // [3072] fp32
  const float* wo_w  = (const float*)d_in[3];  // [1024,1024] fp32
  const float* wo_b  = (const float*)d_in[4];  // [1024] fp32
  const void*  mask  = d_in[5];                // [4,2048] int32/64 (detected)

  if (ws_size < 33554432) return;  // R3-verified: ws >= 32 MiB

  // ws (32 MiB): [0:16) kbuf bf16 / later O copy; [16:22) Wqkv fp16;
  // [22:24) Wo fp16; [24:32) hs16 half-buffer (fp16, 4096 rows).
  // d_out (32 MiB fp32): [0:16) Q bf16 -> O fp16; [16:32) V^T bf16.
  bf16* kbuf = (bf16*)d_ws;
  f16*  wq   = (f16*)((char*)d_ws + 16777216);
  f16*  wo   = (f16*)((char*)d_ws + 16777216 + 6291456);
  f16*  hs16 = (f16*)((char*)d_ws + 25165824);  // 8 MiB half-buffer
  bf16* vbuf = (bf16*)d_out + (size_t)8388608;
  f16*  obuf = (f16*)d_ws;

  // 0. pre-convert + pre-transpose weights to fp16 (once)
  wsplit<<<dim3(96, 32), dim3(32, 8), 0, stream>>>(qkv_w, wq, 1024, 3072);
  wsplit<<<dim3(32, 32), dim3(32, 8), 0, stream>>>(wo_w, wo, 1024, 1024);

  // 1. QKV projection in two M-halves (hs16 half-buffer is 8 MiB):
  //    hconv half -> gemm<1> half (A all-DMA fp16), row_base threads the
  //    global row into the scatter epilogue.
  for (int half = 0; half < 2; ++half) {
    hconv<<<dim3(1024), 256, 0, stream>>>(hs + (size_t)half * 4194304, hs16);
    gemm<1><<<dim3(24, 32), 256, 0, stream>>>(
        hs16, wq, qkv_b, d_out, kbuf, vbuf, 4096, 3072, 1024, half * 4096);
  }

  // 2. fused attention, in-place on d_out[0:16MiB) (O written as fp16)
  attn_fused<<<dim3(16, 64), 256, 0, stream>>>(
      (bf16*)d_out, kbuf, vbuf, mask);

  // 3. O -> ws[0:16MiB) (K dead)
  (void)hipMemcpyAsync(d_ws, d_out, (size_t)16777216, hipMemcpyDeviceToDevice,
                       stream);

  // 4. output projection: fp16 O @ Wo -> fp32 d_out
  gemm<0><<<dim3(8, 64), 256, 0, stream>>>(
      obuf, wo, wo_b, d_out, nullptr, nullptr, 8192, 1024, 1024, 0);
}

// Round 13
// 367.231 us; speedup vs baseline: 1.0673x; 1.0673x over previous
//
#include <hip/hip_runtime.h>
#include <math.h>

typedef __bf16 bf16;
typedef __bf16 bf16x4 __attribute__((ext_vector_type(4)));
typedef __bf16 bf16x8 __attribute__((ext_vector_type(8)));
typedef _Float16 f16;
typedef _Float16 f16x4 __attribute__((ext_vector_type(4)));
typedef _Float16 f16x8 __attribute__((ext_vector_type(8)));
typedef float floatx4 __attribute__((ext_vector_type(4)));
typedef float floatx16 __attribute__((ext_vector_type(16)));
typedef short shortx4 __attribute__((ext_vector_type(4)));

#define MFMA_BF16(a, b, c) __builtin_amdgcn_mfma_f32_16x16x32_bf16((a), (b), (c), 0, 0, 0)
#define MFMA_F16(a, b, c) __builtin_amdgcn_mfma_f32_16x16x32_f16((a), (b), (c), 0, 0, 0)
#define MFMA32_BF16(a, b, c) __builtin_amdgcn_mfma_f32_32x32x16_bf16((a), (b), (c), 0, 0, 0)

// PV matmul 32x32 with K=8 (hedged; zero-pad K=16 fallback is equivalent).
__device__ inline floatx16 MFMA_PV32(bf16x4 a, bf16x4 b, floatx16 c) {
#if __has_builtin(__builtin_amdgcn_mfma_f32_32x32x8_bf16)
  return __builtin_amdgcn_mfma_f32_32x32x8_bf16(a, b, c, 0, 0, 0);
#elif __has_builtin(__builtin_amdgcn_mfma_f32_32x32x8bf16_1k)
  shortx4 as, bs;
  __builtin_memcpy(&as, &a, 8);
  __builtin_memcpy(&bs, &b, 8);
  return __builtin_amdgcn_mfma_f32_32x32x8bf16_1k(as, bs, c, 0, 0, 0);
#else
  bf16 z = (bf16)0.f;
  bf16x8 a8 = {a[0], a[1], a[2], a[3], z, z, z, z};
  bf16x8 b8 = {b[0], b[1], b[2], b[3], z, z, z, z};
  return MFMA32_BF16(a8, b8, c);
#endif
}

__device__ inline float fast_exp2(float x) {
#if __has_builtin(__builtin_amdgcn_exp2f)
  return __builtin_amdgcn_exp2f(x);
#else
  return exp2f(x);
#endif
}

// Direct global->LDS DMA, 16 B per lane. LDS dest is wave-uniform base;
// HW writes lane i at ldst + i*16 (linear; no padding allowed).
__device__ inline void gload16(const void* g, void* l) {
  __builtin_amdgcn_global_load_lds(
      (const __attribute__((address_space(1))) void*)g,
      (__attribute__((address_space(3))) void*)l, 16, 0, 0);
}

// mask int64 (0/1 values): all odd uint32 words are 0. int32: OR is nonzero.
__device__ inline int detect_i64(const void* m_) {
  const unsigned int* m = (const unsigned int*)m_;
  unsigned int o = 0;
  for (int i = 1; i < 256; i += 2) o |= m[i];
  return o == 0;
}

// XCD-aware chunked remap (T1). Requires nwg % 8 == 0 (all our grids comply).
__device__ inline int xcd_swizzle(int bid, int nwg) {
  return (bid & 7) * (nwg >> 3) + (bid >> 3);
}

// ---------------------------------------------------------------------------
// Weights: fp32 [R][C] -> fp16, TRANSPOSED [C][R]. Run once.
// ---------------------------------------------------------------------------
__global__ void wsplit(const float* __restrict__ in, f16* __restrict__ out,
                       int R, int C) {
  __shared__ float tile[32][33];
  int bx = blockIdx.x * 32, by = blockIdx.y * 32;
  int tx = threadIdx.x, ty = threadIdx.y;
#pragma unroll
  for (int i = 0; i < 32; i += 8)
    tile[ty + i][tx] = in[(size_t)(by + ty + i) * C + bx + tx];
  __syncthreads();
#pragma unroll
  for (int i = 0; i < 32; i += 8) {
    float x = tile[tx][ty + i];
    size_t oi = (size_t)(bx + ty + i) * R + by + tx;
    out[oi] = (f16)x;
  }
}

// ---------------------------------------------------------------------------
// C = A[M,K] @ B[K,N] + bias, fp16 single-pass MFMA (R16, verified).
// R12 structure: double-buffered LDS, stage-next-FIRST, ONE barrier per
// K-step; DMA tiles XOR-swizzled both-sides. MODE 1 A (fp32) T14
// async-split. Unchanged.
// ---------------------------------------------------------------------------
template <int MODE>
__global__ __launch_bounds__(256) void gemm(
    const void* __restrict__ Av, const f16* __restrict__ Bg,
    const float* __restrict__ bias, void* __restrict__ Cq,
    bf16* __restrict__ Ck, bf16* __restrict__ Cv, int M, int N, int K) {
  constexpr int APAD = (MODE == 1) ? 40 : 32;
  __shared__ __align__(16) f16 Ah[2][128][APAD];
  __shared__ __align__(16) f16 Bs[2][128][32];

  int tid = threadIdx.x;
  int wave = tid >> 6, lane = tid & 63;
  int quad = lane >> 4, c = lane & 15;
  int wrow = (wave >> 1) * 64, wcol = (wave & 1) * 64;

  int nwg = gridDim.x * gridDim.y;
  int bid = blockIdx.x + gridDim.x * blockIdx.y;
  int nb = xcd_swizzle(bid, nwg);
  int m0 = (nb / gridDim.x) * 128, n0 = (nb % gridDim.x) * 128;

  int srow = lane >> 2;
  int ql8 = (((lane & 3) ^ ((lane >> 3) & 3)) * 8);
  int rswz = (c >> 1) & 3;

  floatx4 zero4 = {0.f, 0.f, 0.f, 0.f};
  floatx4 acc[4][4];
#pragma unroll
  for (int i = 0; i < 4; ++i)
#pragma unroll
    for (int j = 0; j < 4; ++j) acc[i][j] = zero4;

  floatx4 aR[4];

#define STAGE_B(buf, kk)                                                    \
  {                                                                         \
    _Pragma("unroll") for (int u = 0; u < 2; ++u) {                         \
      int ch = wave * 2 + u;                                                \
      size_t gi = (size_t)(n0 + ch * 16 + srow) * K + (kk) + ql8;           \
      gload16(&Bg[gi], &Bs[buf][ch * 16][0]);                               \
    }                                                                       \
  }
#define STAGE_A_DMA(buf, kk)                                                \
  {                                                                         \
    _Pragma("unroll") for (int u = 0; u < 2; ++u) {                         \
      int ch = wave * 2 + u;                                                \
      size_t gi = (size_t)(m0 + ch * 16 + srow) * K + (kk) + ql8;           \
      gload16((const f16*)Av + gi, &Ah[buf][ch * 16][0]);                   \
    }                                                                       \
  }
#define ISSUE_A(kk)                                                         \
  {                                                                         \
    const float* Af = (const float*)Av;                                     \
    _Pragma("unroll") for (int p = 0; p < 2; ++p) {                         \
      int off = p * 2048 + tid * 8;                                         \
      int r = off >> 5, cc = off & 31;                                      \
      size_t gi = (size_t)(m0 + r) * K + (kk) + cc;                         \
      aR[p * 2] = *(const floatx4*)&Af[gi];                                 \
      aR[p * 2 + 1] = *(const floatx4*)&Af[gi + 4];                         \
    }                                                                       \
  }
#define WRITE_A(buf)                                                        \
  {                                                                         \
    _Pragma("unroll") for (int p = 0; p < 2; ++p) {                         \
      int off = p * 2048 + tid * 8;                                         \
      int r = off >> 5, cc = off & 31;                                      \
      f16x8 h;                                                              \
      _Pragma("unroll") for (int uu = 0; uu < 4; ++uu) {                    \
        h[uu] = (f16)aR[p * 2][uu];                                         \
        h[4 + uu] = (f16)aR[p * 2 + 1][uu];                                 \
      }                                                                     \
      *(f16x8*)&Ah[buf][r][cc] = h;                                         \
    }                                                                       \
  }

  STAGE_B(0, 0);
  if constexpr (MODE == 1) {
    ISSUE_A(0);
    WRITE_A(0);
  } else {
    STAGE_A_DMA(0, 0);
  }
  __syncthreads();

  int nk = K / 32;
  int cur = 0;
  for (int t = 0; t < nk; ++t) {
    int kn = (t + 1) * 32;
    bool has_next = (t + 1 < nk);
    if (has_next) {
      STAGE_B(cur ^ 1, kn);
      if constexpr (MODE == 1) {
        ISSUE_A(kn);
      } else {
        STAGE_A_DMA(cur ^ 1, kn);
      }
    }

    f16x8 ah[4], bh[4];
#pragma unroll
    for (int i = 0; i < 4; ++i) {
      if constexpr (MODE == 1)
        ah[i] = *(const f16x8*)&Ah[cur][wrow + i * 16 + c][quad * 8];
      else
        ah[i] = *(const f16x8*)&Ah[cur][wrow + i * 16 + c][(quad ^ rswz) * 8];
    }
#pragma unroll
    for (int j = 0; j < 4; ++j)
      bh[j] = *(const f16x8*)&Bs[cur][wcol + j * 16 + c][(quad ^ rswz) * 8];
#pragma unroll
    for (int i = 0; i < 4; ++i)
#pragma unroll
      for (int j = 0; j < 4; ++j)
        acc[i][j] = MFMA_F16(ah[i], bh[j], acc[i][j]);

    if (has_next) {
      if constexpr (MODE == 1) WRITE_A(cur ^ 1);
      __syncthreads();
      cur ^= 1;
    }
  }
#undef STAGE_B
#undef STAGE_A_DMA
#undef ISSUE_A
#undef WRITE_A

#pragma unroll
  for (int i = 0; i < 4; ++i) {
#pragma unroll
    for (int j = 0; j < 4; ++j) {
      int col = n0 + wcol + j * 16 + c;
      float bvv = bias[col];
#pragma unroll
      for (int r = 0; r < 4; ++r) {
        int row = m0 + wrow + i * 16 + quad * 4 + r;
        float v = acc[i][j][r] + bvv;
        if constexpr (MODE == 0) {
          ((float*)Cq)[(size_t)row * N + col] = v;
        } else {
          int which = col >> 10;          // 0=Q,1=K,2=V (wave-uniform)
          int h = (col >> 6) & 15;
          int d = col & 63;
          int b = row >> 11;
          int s = row & 2047;
          if (which == 0) {
            ((bf16*)Cq)[((size_t)(b * 2048 + s)) * 1024 + h * 64 + d] = (bf16)v;
          } else if (which == 1) {
            Ck[((size_t)(b * 16 + h) * 2048 + s) * 64 + d] = (bf16)v;
          } else {
            Cv[((size_t)(b * 16 + h) * 64 + d) * 2048 + s] = (bf16)v;
          }
        }
      }
    }
  }
}

// ---------------------------------------------------------------------------
// Fused MFMA flash attention (R17): 32x32 MFMA, 128-q blocks. Each wave owns
// 32 q rows (Q in 16 VGPR); block stages K/V (64 keys/kt) in LDS serving 2x
// the q of R13 -> LDS/VALU/staging per FLOP halved. QK^T = 32x32x16 (A=K
// from LDS, B=Q regs): S^T C/D (col=q, row=(reg&3)+8*(reg>>2)+4*hi) reg-
// group 4s..4s+3 IS the K=8 PV B-frag (k=4hi+i) for key-octet 8s -> P feeds
// PV fully in-register, zero shuffles, no Ps LDS. PV = 32x32x8 (A=V^T b64
// reads). R13's verified ping-pong phase schedule kept: phase A {issue V_t,
// QK^T+softmax, write V_t, bar}; phase B {issue K_{t+1}, PV, write K, bar}.
// Mask folded via abuf_all[2048] (precomputed once; broadcast reads).
// O stored fp16 for the fp16 proj GEMM (R16).
// ---------------------------------------------------------------------------
__global__ __launch_bounds__(256) void attn_fused(
    bf16* QO, const bf16* __restrict__ Kg, const bf16* __restrict__ Vg,
    const void* __restrict__ mask) {
  __shared__ __align__(16) bf16 Ks[64][72];   // [key][d]
  __shared__ __align__(16) bf16 Vts[64][72];  // [d][key]
  __shared__ __align__(16) float abuf_all[2048];  // mv ? -12 : -1e30

  const int i64 = detect_i64(mask);

  int tid = threadIdx.x;
  int wave = tid >> 6, lane = tid & 63;
  int l31 = lane & 31, hi = lane >> 5;

  // T1: XCD-chunked remap; consecutive new ids share bh -> K/V L2 reuse.
  int nwg = gridDim.x * gridDim.y;  // 1024
  int bid = blockIdx.x + gridDim.x * blockIdx.y;
  int nb = xcd_swizzle(bid, nwg);
  int qt = nb & 15, bh = nb >> 4;

  int b = bh >> 4, h = bh & 15;
  int q0 = qt * 128;
  bf16* Qp = QO + (size_t)b * 2048 * 1024 + h * 64;  // row stride 1024
  const bf16* Kp = Kg + (size_t)bh * 2048 * 64;      // [s][d]
  const bf16* Vp = Vg + (size_t)bh * 64 * 2048;      // [d][s] (transposed)

  // mask table for all 2048 keys of batch b (once, read-only after barrier)
#pragma unroll
  for (int i = 0; i < 8; ++i) {
    int key = tid * 8 + i;
    int idx = b * 2048 + key;
    int mv = i64 ? (int)((const long long*)mask)[idx]
                 : ((const int*)mask)[idx];
    abuf_all[key] = mv ? -12.0f : -1e30f;
  }

  // Q frags (B-operand of 32x32x16 QK^T): col q = l31, k = hi*8+i per dstep.
  int qrow = q0 + wave * 32 + l31;
  bf16x8 qf[4];
#pragma unroll
  for (int ds = 0; ds < 4; ++ds)
    qf[ds] = *(const bf16x8*)&Qp[(size_t)qrow * 1024 + ds * 16 + hi * 8];

  floatx16 o[2];
#pragma unroll
  for (int dt = 0; dt < 2; ++dt)
#pragma unroll
    for (int i = 0; i < 16; ++i) o[dt][i] = 0.f;
  float lacc = 0.f;

  // prologue: stage K_0
#pragma unroll
  for (int p = 0; p < 2; ++p) {
    int off = p * 2048 + tid * 8;
    int r = off >> 6, cc = off & 63;
    *(bf16x8*)&Ks[r][cc] = *(const bf16x8*)&Kp[(size_t)r * 64 + cc];
  }
  __syncthreads();  // Ks_0 + abuf_all visible

  bf16x4 pk[8];  // P^T frags: pk[t2*4+s] = keys t2*32 + 8s + 4hi + j

  for (int kt = 0; kt < 32; ++kt) {
    int k0 = kt * 64;

    // ---- phase A: issue V_t; QK^T both tiles; softmax->pk; write V_t ----
    bf16x8 vstage[2];
#pragma unroll
    for (int p = 0; p < 2; ++p) {
      int off = p * 2048 + tid * 8;
      int r = off >> 6, cc = off & 63;
      vstage[p] = *(const bf16x8*)&Vp[(size_t)r * 2048 + k0 + cc];
    }

#pragma unroll
    for (int t2 = 0; t2 < 2; ++t2) {
      floatx16 sr;
#pragma unroll
      for (int i = 0; i < 16; ++i) sr[i] = 0.f;
#pragma unroll
      for (int ds = 0; ds < 4; ++ds) {
        bf16x8 ak = *(const bf16x8*)&Ks[t2 * 32 + l31][ds * 16 + hi * 8];
        sr = MFMA32_BF16(ak, qf[ds], sr);
      }
      // softmax in-register; reg group 4s..4s+3 -> keys t2*32+8s+4hi+j
#pragma unroll
      for (int s = 0; s < 4; ++s) {
        floatx4 am = *(const floatx4*)&abuf_all[k0 + t2 * 32 + s * 8 + hi * 4];
        bf16x4 p4;
#pragma unroll
        for (int j = 0; j < 4; ++j) {
          float pv = __expf(fmaf(sr[s * 4 + j], 0.125f, am[j]));
          lacc += pv;
          p4[j] = (bf16)pv;
        }
        pk[t2 * 4 + s] = p4;
      }
    }

    // write V_t (vstage vmcnt hidden under QK^T/softmax)
#pragma unroll
    for (int p = 0; p < 2; ++p) {
      int off = p * 2048 + tid * 8;
      int r = off >> 6, cc = off & 63;
      *(bf16x8*)&Vts[r][cc] = vstage[p];
    }
    __syncthreads();  // V_t visible; Ks free for overwrite

    // ---- phase B: issue K_{t+1}; PV; write K_{t+1} ----
    bf16x8 kstage[2];
    bool more = (kt + 1) < 32;
    int kn = k0 + 64;
    if (more) {
#pragma unroll
      for (int p = 0; p < 2; ++p) {
        int off = p * 2048 + tid * 8;
        int r = off >> 6, cc = off & 63;
        kstage[p] = *(const bf16x8*)&Kp[(size_t)(kn + r) * 64 + cc];
      }
    }

    // O^T += V^T @ P^T: A = Vts[dt*32+l31][ss*8+hi*4] (b64), B = pk[ss]
#pragma unroll
    for (int ss = 0; ss < 8; ++ss) {
#pragma unroll
      for (int dt = 0; dt < 2; ++dt) {
        bf16x4 av = *(const bf16x4*)&Vts[dt * 32 + l31][ss * 8 + hi * 4];
        o[dt] = MFMA_PV32(av, pk[ss], o[dt]);
      }
    }

    if (more) {
#pragma unroll
      for (int p = 0; p < 2; ++p) {
        int off = p * 2048 + tid * 8;
        int r = off >> 6, cc = off & 63;
        *(bf16x8*)&Ks[r][cc] = kstage[p];
      }
      __syncthreads();  // K_{t+1} visible; Vts free
    }
  }

  // l(q) = own half (this hi's 32 keys/kt) + partner half
  lacc += __shfl_xor(lacc, 32, 64);
  float inv = 1.0f / fmaxf(lacc, 1e-30f);

  // O^T C/D: col q = l31, row d_local = (reg&3)+8*(reg>>2)+4*hi (+32*dt).
  // Store fp16, groups of 4 consecutive d.
#pragma unroll
  for (int dt = 0; dt < 2; ++dt) {
#pragma unroll
    for (int t = 0; t < 4; ++t) {
      f16x4 out;
#pragma unroll
      for (int j = 0; j < 4; ++j) out[j] = (f16)(o[dt][t * 4 + j] * inv);
      int d0 = dt * 32 + t * 8 + hi * 4;
      *(f16x4*)((f16*)&Qp[(size_t)qrow * 1024] + d0) = out;
    }
  }
}

// ---------------------------------------------------------------------------
extern "C" void kernel_launch(void* const* d_in, const int* in_sizes, int n_in,
                              void* d_out, int out_size, void* d_ws, size_t ws_size,
                              hipStream_t stream) {
  (void)in_sizes; (void)n_in; (void)out_size;
  const float* hs    = (const float*)d_in[0];  // [4,2048,1024] fp32
  const float* qkv_w = (const float*)d_in[1];  // [1024,3072] fp32
  const float* qkv_b = (const float*)d_in[2];  // [3072] fp32
  const float* wo_w  = (const float*)d_in[3];  // [1024,1024] fp32
  const float* wo_b  = (const float*)d_in[4];  // [1024] fp32
  const void*  mask  = d_in[5];                // [4,2048] int32/64 (detected)

  if (ws_size < 33554432) return;  // R3-verified: ws >= 32 MiB

  // ws (32 MiB): [0:16MiB) K bf16, later O copy; [16MiB:+6MiB) Wqkv fp16;
  // [+22MiB:+2MiB) Wo fp16. d_out (32 MiB fp32): [0:16MiB) Q->O; [16:32MiB)
  // V^T bf16 (both dead before the fp32 proj store).
  bf16* kbuf = (bf16*)d_ws;
  f16*  wq   = (f16*)((char*)d_ws + 16777216);            // 3072*1024 fp16
  f16*  wo   = (f16*)((char*)d_ws + 16777216 + 6291456);  // 1024*1024 fp16
  bf16* vbuf = (bf16*)d_out + (size_t)8388608;
  f16*  obuf = (f16*)d_ws;

  // 0. pre-convert + pre-transpose weights to fp16 (once)
  wsplit<<<dim3(96, 32), dim3(32, 8), 0, stream>>>(qkv_w, wq, 1024, 3072);
  wsplit<<<dim3(32, 32), dim3(32, 8), 0, stream>>>(wo_w, wo, 1024, 1024);

  // 1. QKV projection: Q -> d_out[0:16MiB), K -> ws, V^T -> d_out[16:32MiB)
  gemm<1><<<dim3(24, 64), 256, 0, stream>>>(
      hs, wq, qkv_b, d_out, kbuf, vbuf, 8192, 3072, 1024);

  // 2. fused attention, in-place on d_out[0:16MiB) (O written as fp16)
  attn_fused<<<dim3(16, 64), 256, 0, stream>>>(
      (bf16*)d_out, kbuf, vbuf, mask);

  // 3. O -> ws[0:16MiB) (K dead)
  (void)hipMemcpyAsync(d_ws, d_out, (size_t)16777216, hipMemcpyDeviceToDevice,
                       stream);

  // 4. output projection: fp16 O @ Wo -> fp32 d_out
  gemm<0><<<dim3(8, 64), 256, 0, stream>>>(
      obuf, wo, wo_b, d_out, nullptr, nullptr, 8192, 1024, 1024);
}

// Round 14
// 355.991 us; speedup vs baseline: 1.1010x; 1.0316x over previous
//
#include <hip/hip_runtime.h>
#include <math.h>

typedef __bf16 bf16;
typedef __bf16 bf16x4 __attribute__((ext_vector_type(4)));
typedef __bf16 bf16x8 __attribute__((ext_vector_type(8)));
typedef _Float16 f16;
typedef _Float16 f16x4 __attribute__((ext_vector_type(4)));
typedef _Float16 f16x8 __attribute__((ext_vector_type(8)));
typedef float floatx4 __attribute__((ext_vector_type(4)));
typedef float floatx16 __attribute__((ext_vector_type(16)));
typedef short shortx4 __attribute__((ext_vector_type(4)));

#define MFMA_BF16(a, b, c) __builtin_amdgcn_mfma_f32_16x16x32_bf16((a), (b), (c), 0, 0, 0)
#define MFMA_F16(a, b, c) __builtin_amdgcn_mfma_f32_16x16x32_f16((a), (b), (c), 0, 0, 0)
#define MFMA32_BF16(a, b, c) __builtin_amdgcn_mfma_f32_32x32x16_bf16((a), (b), (c), 0, 0, 0)

// PV matmul 32x32 with K=8 (hedged; zero-pad K=16 fallback is equivalent).
__device__ inline floatx16 MFMA_PV32(bf16x4 a, bf16x4 b, floatx16 c) {
#if __has_builtin(__builtin_amdgcn_mfma_f32_32x32x8_bf16)
  return __builtin_amdgcn_mfma_f32_32x32x8_bf16(a, b, c, 0, 0, 0);
#elif __has_builtin(__builtin_amdgcn_mfma_f32_32x32x8bf16_1k)
  shortx4 as, bs;
  __builtin_memcpy(&as, &a, 8);
  __builtin_memcpy(&bs, &b, 8);
  return __builtin_amdgcn_mfma_f32_32x32x8bf16_1k(as, bs, c, 0, 0, 0);
#else
  bf16 z = (bf16)0.f;
  bf16x8 a8 = {a[0], a[1], a[2], a[3], z, z, z, z};
  bf16x8 b8 = {b[0], b[1], b[2], b[3], z, z, z, z};
  return MFMA32_BF16(a8, b8, c);
#endif
}

__device__ inline float fast_exp2(float x) {
#if __has_builtin(__builtin_amdgcn_exp2f)
  return __builtin_amdgcn_exp2f(x);
#else
  return exp2f(x);
#endif
}

// Direct global->LDS DMA, 16 B per lane. LDS dest is wave-uniform base;
// HW writes lane i at ldst + i*16 (linear; no padding allowed).
__device__ inline void gload16(const void* g, void* l) {
  __builtin_amdgcn_global_load_lds(
      (const __attribute__((address_space(1))) void*)g,
      (__attribute__((address_space(3))) void*)l, 16, 0, 0);
}

// mask int64 (0/1 values): all odd uint32 words are 0. int32: OR is nonzero.
__device__ inline int detect_i64(const void* m_) {
  const unsigned int* m = (const unsigned int*)m_;
  unsigned int o = 0;
  for (int i = 1; i < 256; i += 2) o |= m[i];
  return o == 0;
}

// XCD-aware chunked remap (T1). Requires nwg % 8 == 0 (all our grids comply).
__device__ inline int xcd_swizzle(int bid, int nwg) {
  return (bid & 7) * (nwg >> 3) + (bid >> 3);
}

// ---------------------------------------------------------------------------
// Weights: fp32 [R][C] -> fp16, TRANSPOSED [C][R]. Run once.
// ---------------------------------------------------------------------------
__global__ void wsplit(const float* __restrict__ in, f16* __restrict__ out,
                       int R, int C) {
  __shared__ float tile[32][33];
  int bx = blockIdx.x * 32, by = blockIdx.y * 32;
  int tx = threadIdx.x, ty = threadIdx.y;
#pragma unroll
  for (int i = 0; i < 32; i += 8)
    tile[ty + i][tx] = in[(size_t)(by + ty + i) * C + bx + tx];
  __syncthreads();
#pragma unroll
  for (int i = 0; i < 32; i += 8) {
    float x = tile[tx][ty + i];
    size_t oi = (size_t)(bx + ty + i) * R + by + tx;
    out[oi] = (f16)x;
  }
}

// ---------------------------------------------------------------------------
// C = A[M,K] @ B[K,N] + bias, fp16 single-pass MFMA (R16, verified).
// R12 structure: double-buffered LDS, stage-next-FIRST, ONE barrier per
// K-step; DMA tiles XOR-swizzled both-sides. MODE 1 A (fp32) T14
// async-split. Unchanged (m190: setprio null on 2-phase GEMM — not applied).
// ---------------------------------------------------------------------------
template <int MODE>
__global__ __launch_bounds__(256) void gemm(
    const void* __restrict__ Av, const f16* __restrict__ Bg,
    const float* __restrict__ bias, void* __restrict__ Cq,
    bf16* __restrict__ Ck, bf16* __restrict__ Cv, int M, int N, int K) {
  constexpr int APAD = (MODE == 1) ? 40 : 32;
  __shared__ __align__(16) f16 Ah[2][128][APAD];
  __shared__ __align__(16) f16 Bs[2][128][32];

  int tid = threadIdx.x;
  int wave = tid >> 6, lane = tid & 63;
  int quad = lane >> 4, c = lane & 15;
  int wrow = (wave >> 1) * 64, wcol = (wave & 1) * 64;

  int nwg = gridDim.x * gridDim.y;
  int bid = blockIdx.x + gridDim.x * blockIdx.y;
  int nb = xcd_swizzle(bid, nwg);
  int m0 = (nb / gridDim.x) * 128, n0 = (nb % gridDim.x) * 128;

  int srow = lane >> 2;
  int ql8 = (((lane & 3) ^ ((lane >> 3) & 3)) * 8);
  int rswz = (c >> 1) & 3;

  floatx4 zero4 = {0.f, 0.f, 0.f, 0.f};
  floatx4 acc[4][4];
#pragma unroll
  for (int i = 0; i < 4; ++i)
#pragma unroll
    for (int j = 0; j < 4; ++j) acc[i][j] = zero4;

  floatx4 aR[4];

#define STAGE_B(buf, kk)                                                    \
  {                                                                         \
    _Pragma("unroll") for (int u = 0; u < 2; ++u) {                         \
      int ch = wave * 2 + u;                                                \
      size_t gi = (size_t)(n0 + ch * 16 + srow) * K + (kk) + ql8;           \
      gload16(&Bg[gi], &Bs[buf][ch * 16][0]);                               \
    }                                                                       \
  }
#define STAGE_A_DMA(buf, kk)                                                \
  {                                                                         \
    _Pragma("unroll") for (int u = 0; u < 2; ++u) {                         \
      int ch = wave * 2 + u;                                                \
      size_t gi = (size_t)(m0 + ch * 16 + srow) * K + (kk) + ql8;           \
      gload16((const f16*)Av + gi, &Ah[buf][ch * 16][0]);                   \
    }                                                                       \
  }
#define ISSUE_A(kk)                                                         \
  {                                                                         \
    const float* Af = (const float*)Av;                                     \
    _Pragma("unroll") for (int p = 0; p < 2; ++p) {                         \
      int off = p * 2048 + tid * 8;                                         \
      int r = off >> 5, cc = off & 31;                                      \
      size_t gi = (size_t)(m0 + r) * K + (kk) + cc;                         \
      aR[p * 2] = *(const floatx4*)&Af[gi];                                 \
      aR[p * 2 + 1] = *(const floatx4*)&Af[gi + 4];                         \
    }                                                                       \
  }
#define WRITE_A(buf)                                                        \
  {                                                                         \
    _Pragma("unroll") for (int p = 0; p < 2; ++p) {                         \
      int off = p * 2048 + tid * 8;                                         \
      int r = off >> 5, cc = off & 31;                                      \
      f16x8 h;                                                              \
      _Pragma("unroll") for (int uu = 0; uu < 4; ++uu) {                    \
        h[uu] = (f16)aR[p * 2][uu];                                         \
        h[4 + uu] = (f16)aR[p * 2 + 1][uu];                                 \
      }                                                                     \
      *(f16x8*)&Ah[buf][r][cc] = h;                                         \
    }                                                                       \
  }

  STAGE_B(0, 0);
  if constexpr (MODE == 1) {
    ISSUE_A(0);
    WRITE_A(0);
  } else {
    STAGE_A_DMA(0, 0);
  }
  __syncthreads();

  int nk = K / 32;
  int cur = 0;
  for (int t = 0; t < nk; ++t) {
    int kn = (t + 1) * 32;
    bool has_next = (t + 1 < nk);
    if (has_next) {
      STAGE_B(cur ^ 1, kn);
      if constexpr (MODE == 1) {
        ISSUE_A(kn);
      } else {
        STAGE_A_DMA(cur ^ 1, kn);
      }
    }

    f16x8 ah[4], bh[4];
#pragma unroll
    for (int i = 0; i < 4; ++i) {
      if constexpr (MODE == 1)
        ah[i] = *(const f16x8*)&Ah[cur][wrow + i * 16 + c][quad * 8];
      else
        ah[i] = *(const f16x8*)&Ah[cur][wrow + i * 16 + c][(quad ^ rswz) * 8];
    }
#pragma unroll
    for (int j = 0; j < 4; ++j)
      bh[j] = *(const f16x8*)&Bs[cur][wcol + j * 16 + c][(quad ^ rswz) * 8];
#pragma unroll
    for (int i = 0; i < 4; ++i)
#pragma unroll
      for (int j = 0; j < 4; ++j)
        acc[i][j] = MFMA_F16(ah[i], bh[j], acc[i][j]);

    if (has_next) {
      if constexpr (MODE == 1) WRITE_A(cur ^ 1);
      __syncthreads();
      cur ^= 1;
    }
  }
#undef STAGE_B
#undef STAGE_A_DMA
#undef ISSUE_A
#undef WRITE_A

#pragma unroll
  for (int i = 0; i < 4; ++i) {
#pragma unroll
    for (int j = 0; j < 4; ++j) {
      int col = n0 + wcol + j * 16 + c;
      float bvv = bias[col];
#pragma unroll
      for (int r = 0; r < 4; ++r) {
        int row = m0 + wrow + i * 16 + quad * 4 + r;
        float v = acc[i][j][r] + bvv;
        if constexpr (MODE == 0) {
          ((float*)Cq)[(size_t)row * N + col] = v;
        } else {
          int which = col >> 10;          // 0=Q,1=K,2=V (wave-uniform)
          int h = (col >> 6) & 15;
          int d = col & 63;
          int b = row >> 11;
          int s = row & 2047;
          if (which == 0) {
            ((bf16*)Cq)[((size_t)(b * 2048 + s)) * 1024 + h * 64 + d] = (bf16)v;
          } else if (which == 1) {
            Ck[((size_t)(b * 16 + h) * 2048 + s) * 64 + d] = (bf16)v;
          } else {
            Cv[((size_t)(b * 16 + h) * 64 + d) * 2048 + s] = (bf16)v;
          }
        }
      }
    }
  }
}

// ---------------------------------------------------------------------------
// Fused MFMA flash attention (R20 = verified R17 + T5 setprio around both
// MFMA clusters [m191: +4-7% on phase-split attn] + exp2 constant-fold
// [identity: exp(x/8-12) = exp2(x*0.125*log2e - 12*log2e), removes the
// hidden v_mul in __expf]). Structure unchanged: 32x32 MFMA, 128-q blocks,
// reg-staged K/V ping-pong phases, in-register P (S^T C/D reg-group ==
// K=8 PV B-frag). O stored fp16 for the fp16 proj GEMM.
// ---------------------------------------------------------------------------
__global__ __launch_bounds__(256) void attn_fused(
    bf16* QO, const bf16* __restrict__ Kg, const bf16* __restrict__ Vg,
    const void* __restrict__ mask) {
  __shared__ __align__(16) bf16 Ks[64][72];   // [key][d]
  __shared__ __align__(16) bf16 Vts[64][72];  // [d][key]
  __shared__ __align__(16) float abuf_all[2048];  // mv ? -12*log2e : -1e30

  const int i64 = detect_i64(mask);

  int tid = threadIdx.x;
  int wave = tid >> 6, lane = tid & 63;
  int l31 = lane & 31, hi = lane >> 5;

  // T1: XCD-chunked remap; consecutive new ids share bh -> K/V L2 reuse.
  int nwg = gridDim.x * gridDim.y;  // 1024
  int bid = blockIdx.x + gridDim.x * blockIdx.y;
  int nb = xcd_swizzle(bid, nwg);
  int qt = nb & 15, bh = nb >> 4;

  int b = bh >> 4, h = bh & 15;
  int q0 = qt * 128;
  bf16* Qp = QO + (size_t)b * 2048 * 1024 + h * 64;  // row stride 1024
  const bf16* Kp = Kg + (size_t)bh * 2048 * 64;      // [s][d]
  const bf16* Vp = Vg + (size_t)bh * 64 * 2048;      // [d][s] (transposed)

  // mask table for all 2048 keys of batch b (log2e units; once, read-only)
#pragma unroll
  for (int i = 0; i < 8; ++i) {
    int key = tid * 8 + i;
    int idx = b * 2048 + key;
    int mv = i64 ? (int)((const long long*)mask)[idx]
                 : ((const int*)mask)[idx];
    abuf_all[key] = mv ? -17.3123404907f : -1e30f;
  }

  // Q frags (B-operand of 32x32x16 QK^T): col q = l31, k = hi*8+i per dstep.
  int qrow = q0 + wave * 32 + l31;
  bf16x8 qf[4];
#pragma unroll
  for (int ds = 0; ds < 4; ++ds)
    qf[ds] = *(const bf16x8*)&Qp[(size_t)qrow * 1024 + ds * 16 + hi * 8];

  floatx16 o[2];
#pragma unroll
  for (int dt = 0; dt < 2; ++dt)
#pragma unroll
    for (int i = 0; i < 16; ++i) o[dt][i] = 0.f;
  float lacc = 0.f;

  // prologue: stage K_0
#pragma unroll
  for (int p = 0; p < 2; ++p) {
    int off = p * 2048 + tid * 8;
    int r = off >> 6, cc = off & 63;
    *(bf16x8*)&Ks[r][cc] = *(const bf16x8*)&Kp[(size_t)r * 64 + cc];
  }
  __syncthreads();  // Ks_0 + abuf_all visible

  bf16x4 pk[8];  // P^T frags: pk[t2*4+s] = keys t2*32 + 8s + 4hi + j

  for (int kt = 0; kt < 32; ++kt) {
    int k0 = kt * 64;

    // ---- phase A: issue V_t; QK^T both tiles; softmax->pk; write V_t ----
    bf16x8 vstage[2];
#pragma unroll
    for (int p = 0; p < 2; ++p) {
      int off = p * 2048 + tid * 8;
      int r = off >> 6, cc = off & 63;
      vstage[p] = *(const bf16x8*)&Vp[(size_t)r * 2048 + k0 + cc];
    }

#pragma unroll
    for (int t2 = 0; t2 < 2; ++t2) {
      floatx16 sr;
#pragma unroll
      for (int i = 0; i < 16; ++i) sr[i] = 0.f;
      // T5: favor this wave while it owns the matrix pipe
      __builtin_amdgcn_s_setprio(1);
#pragma unroll
      for (int ds = 0; ds < 4; ++ds) {
        bf16x8 ak = *(const bf16x8*)&Ks[t2 * 32 + l31][ds * 16 + hi * 8];
        sr = MFMA32_BF16(ak, qf[ds], sr);
      }
      __builtin_amdgcn_s_setprio(0);
      // softmax in-register; reg group 4s..4s+3 -> keys t2*32+8s+4hi+j
#pragma unroll
      for (int s = 0; s < 4; ++s) {
        floatx4 am = *(const floatx4*)&abuf_all[k0 + t2 * 32 + s * 8 + hi * 4];
        bf16x4 p4;
#pragma unroll
        for (int j = 0; j < 4; ++j) {
          // exp(x/8 - 12) == exp2(x*0.125*log2e - 12*log2e)
          float pv = fast_exp2(fmaf(sr[s * 4 + j], 0.1803368801f, am[j]));
          lacc += pv;
          p4[j] = (bf16)pv;
        }
        pk[t2 * 4 + s] = p4;
      }
    }

    // write V_t (vstage vmcnt hidden under QK^T/softmax)
#pragma unroll
    for (int p = 0; p < 2; ++p) {
      int off = p * 2048 + tid * 8;
      int r = off >> 6, cc = off & 63;
      *(bf16x8*)&Vts[r][cc] = vstage[p];
    }
    __syncthreads();  // V_t visible; Ks free for overwrite

    // ---- phase B: issue K_{t+1}; PV; write K_{t+1} ----
    bf16x8 kstage[2];
    bool more = (kt + 1) < 32;
    int kn = k0 + 64;
    if (more) {
#pragma unroll
      for (int p = 0; p < 2; ++p) {
        int off = p * 2048 + tid * 8;
        int r = off >> 6, cc = off & 63;
        kstage[p] = *(const bf16x8*)&Kp[(size_t)(kn + r) * 64 + cc];
      }
    }

    // O^T += V^T @ P^T: A = Vts[dt*32+l31][ss*8+hi*4] (b64), B = pk[ss]
    __builtin_amdgcn_s_setprio(1);
#pragma unroll
    for (int ss = 0; ss < 8; ++ss) {
#pragma unroll
      for (int dt = 0; dt < 2; ++dt) {
        bf16x4 av = *(const bf16x4*)&Vts[dt * 32 + l31][ss * 8 + hi * 4];
        o[dt] = MFMA_PV32(av, pk[ss], o[dt]);
      }
    }
    __builtin_amdgcn_s_setprio(0);

    if (more) {
#pragma unroll
      for (int p = 0; p < 2; ++p) {
        int off = p * 2048 + tid * 8;
        int r = off >> 6, cc = off & 63;
        *(bf16x8*)&Ks[r][cc] = kstage[p];
      }
      __syncthreads();  // K_{t+1} visible; Vts free
    }
  }

  // l(q) = own half (this hi's 32 keys/kt) + partner half
  lacc += __shfl_xor(lacc, 32, 64);
  float inv = 1.0f / fmaxf(lacc, 1e-30f);

  // O^T C/D: col q = l31, row d_local = (reg&3)+8*(reg>>2)+4*hi (+32*dt).
  // Store fp16, groups of 4 consecutive d.
#pragma unroll
  for (int dt = 0; dt < 2; ++dt) {
#pragma unroll
    for (int t = 0; t < 4; ++t) {
      f16x4 out;
#pragma unroll
      for (int j = 0; j < 4; ++j) out[j] = (f16)(o[dt][t * 4 + j] * inv);
      int d0 = dt * 32 + t * 8 + hi * 4;
      *(f16x4*)((f16*)&Qp[(size_t)qrow * 1024] + d0) = out;
    }
  }
}

// ---------------------------------------------------------------------------
extern "C" void kernel_launch(void* const* d_in, const int* in_sizes, int n_in,
                              void* d_out, int out_size, void* d_ws, size_t ws_size,
                              hipStream_t stream) {
  (void)in_sizes; (void)n_in; (void)out_size;
  const float* hs    = (const float*)d_in[0];  // [4,2048,1024] fp32
  const float* qkv_w = (const float*)d_in[1];  // [1024,3072] fp32
  const float* qkv_b = (const float*)d_in[2];  // [3072] fp32
  const float* wo_w  = (const float*)d_in[3];  // [1024,1024] fp32
  const float* wo_b  = (const float*)d_in[4];  // [1024] fp32
  const void*  mask  = d_in[5];                // [4,2048] int32/64 (detected)

  if (ws_size < 33554432) return;  // R3-verified: ws >= 32 MiB

  // ws (32 MiB): [0:16MiB) K bf16, later O copy; [16MiB:+6MiB) Wqkv fp16;
  // [+22MiB:+2MiB) Wo fp16. d_out (32 MiB fp32): [0:16MiB) Q->O; [16:32MiB)
  // V^T bf16 (both dead before the fp32 proj store).
  bf16* kbuf = (bf16*)d_ws;
  f16*  wq   = (f16*)((char*)d_ws + 16777216);            // 3072*1024 fp16
  f16*  wo   = (f16*)((char*)d_ws + 16777216 + 6291456);  // 1024*1024 fp16
  bf16* vbuf = (bf16*)d_out + (size_t)8388608;
  f16*  obuf = (f16*)d_ws;

  // 0. pre-convert + pre-transpose weights to fp16 (once)
  wsplit<<<dim3(96, 32), dim3(32, 8), 0, stream>>>(qkv_w, wq, 1024, 3072);
  wsplit<<<dim3(32, 32), dim3(32, 8), 0, stream>>>(wo_w, wo, 1024, 1024);

  // 1. QKV projection: Q -> d_out[0:16MiB), K -> ws, V^T -> d_out[16:32MiB)
  gemm<1><<<dim3(24, 64), 256, 0, stream>>>(
      hs, wq, qkv_b, d_out, kbuf, vbuf, 8192, 3072, 1024);

  // 2. fused attention, in-place on d_out[0:16MiB) (O written as fp16)
  attn_fused<<<dim3(16, 64), 256, 0, stream>>>(
      (bf16*)d_out, kbuf, vbuf, mask);

  // 3. O -> ws[0:16MiB) (K dead)
  (void)hipMemcpyAsync(d_ws, d_out, (size_t)16777216, hipMemcpyDeviceToDevice,
                       stream);

  // 4. output projection: fp16 O @ Wo -> fp32 d_out
  gemm<0><<<dim3(8, 64), 256, 0, stream>>>(
      obuf, wo, wo_b, d_out, nullptr, nullptr, 8192, 1024, 1024);
}

// Round 15
// 340.139 us; speedup vs baseline: 1.1523x; 1.0466x over previous
//
#include <hip/hip_runtime.h>
#include <math.h>

typedef __bf16 bf16;
typedef __bf16 bf16x4 __attribute__((ext_vector_type(4)));
typedef __bf16 bf16x8 __attribute__((ext_vector_type(8)));
typedef _Float16 f16;
typedef _Float16 f16x4 __attribute__((ext_vector_type(4)));
typedef _Float16 f16x8 __attribute__((ext_vector_type(8)));
typedef float floatx4 __attribute__((ext_vector_type(4)));
typedef float floatx16 __attribute__((ext_vector_type(16)));
typedef unsigned int uintx2 __attribute__((ext_vector_type(2)));

#define MFMA_F16(a, b, c) __builtin_amdgcn_mfma_f32_16x16x32_f16((a), (b), (c), 0, 0, 0)
#define MFMA32_BF16(a, b, c) __builtin_amdgcn_mfma_f32_32x32x16_bf16((a), (b), (c), 0, 0, 0)

__device__ inline float fast_exp2(float x) {
#if __has_builtin(__builtin_amdgcn_exp2f)
  return __builtin_amdgcn_exp2f(x);
#else
  return exp2f(x);
#endif
}

// Cross-half pair exchange (T12 primitive): given a (held by all lanes) and
// b, produce lo = {a.row0, b.row0}, hi = {a.row1, b.row1} where rows are the
// lane<32 / lane>=32 halves. permlane32_swap does this in one op per pair;
// explicit shfl_xor fallback is semantics-certain.
__device__ inline void half_swap(unsigned a, unsigned b, int hiLane,
                                 unsigned& lo, unsigned& hiw) {
#if __has_builtin(__builtin_amdgcn_permlane32_swap)
  uintx2 r = __builtin_amdgcn_permlane32_swap(a, b, false, false);
  lo = r[0];
  hiw = r[1];
#else
  unsigned sa = (unsigned)__shfl_xor((int)a, 32, 64);
  unsigned sb = (unsigned)__shfl_xor((int)b, 32, 64);
  lo = hiLane ? sb : a;   // {a.row0, b.row0}
  hiw = hiLane ? b : sa;  // {a.row1, b.row1}
#endif
}

// Direct global->LDS DMA, 16 B per lane. LDS dest is wave-uniform base;
// HW writes lane i at ldst + i*16 (linear; no padding allowed).
__device__ inline void gload16(const void* g, void* l) {
  __builtin_amdgcn_global_load_lds(
      (const __attribute__((address_space(1))) void*)g,
      (__attribute__((address_space(3))) void*)l, 16, 0, 0);
}

// mask int64 (0/1 values): all odd uint32 words are 0. int32: OR is nonzero.
__device__ inline int detect_i64(const void* m_) {
  const unsigned int* m = (const unsigned int*)m_;
  unsigned int o = 0;
  for (int i = 1; i < 256; i += 2) o |= m[i];
  return o == 0;
}

// XCD-aware chunked remap (T1). Requires nwg % 8 == 0 (all our grids comply).
__device__ inline int xcd_swizzle(int bid, int nwg) {
  return (bid & 7) * (nwg >> 3) + (bid >> 3);
}

// ---------------------------------------------------------------------------
// Weights: fp32 [R][C] -> fp16, TRANSPOSED [C][R]. Run once.
// ---------------------------------------------------------------------------
__global__ void wsplit(const float* __restrict__ in, f16* __restrict__ out,
                       int R, int C) {
  __shared__ float tile[32][33];
  int bx = blockIdx.x * 32, by = blockIdx.y * 32;
  int tx = threadIdx.x, ty = threadIdx.y;
#pragma unroll
  for (int i = 0; i < 32; i += 8)
    tile[ty + i][tx] = in[(size_t)(by + ty + i) * C + bx + tx];
  __syncthreads();
#pragma unroll
  for (int i = 0; i < 32; i += 8) {
    float x = tile[tx][ty + i];
    size_t oi = (size_t)(bx + ty + i) * R + by + tx;
    out[oi] = (f16)x;
  }
}

// ---------------------------------------------------------------------------
// C = A[M,K] @ B[K,N] + bias, fp16 single-pass MFMA (R16, verified).
// R12 structure: double-buffered LDS, stage-next-FIRST, ONE barrier per
// K-step; DMA tiles XOR-swizzled both-sides. MODE 1 A (fp32) T14
// async-split. Unchanged (m190: setprio null on 2-phase GEMM — not applied).
// ---------------------------------------------------------------------------
template <int MODE>
__global__ __launch_bounds__(256) void gemm(
    const void* __restrict__ Av, const f16* __restrict__ Bg,
    const float* __restrict__ bias, void* __restrict__ Cq,
    bf16* __restrict__ Ck, bf16* __restrict__ Cv, int M, int N, int K) {
  constexpr int APAD = (MODE == 1) ? 40 : 32;
  __shared__ __align__(16) f16 Ah[2][128][APAD];
  __shared__ __align__(16) f16 Bs[2][128][32];

  int tid = threadIdx.x;
  int wave = tid >> 6, lane = tid & 63;
  int quad = lane >> 4, c = lane & 15;
  int wrow = (wave >> 1) * 64, wcol = (wave & 1) * 64;

  int nwg = gridDim.x * gridDim.y;
  int bid = blockIdx.x + gridDim.x * blockIdx.y;
  int nb = xcd_swizzle(bid, nwg);
  int m0 = (nb / gridDim.x) * 128, n0 = (nb % gridDim.x) * 128;

  int srow = lane >> 2;
  int ql8 = (((lane & 3) ^ ((lane >> 3) & 3)) * 8);
  int rswz = (c >> 1) & 3;

  floatx4 zero4 = {0.f, 0.f, 0.f, 0.f};
  floatx4 acc[4][4];
#pragma unroll
  for (int i = 0; i < 4; ++i)
#pragma unroll
    for (int j = 0; j < 4; ++j) acc[i][j] = zero4;

  floatx4 aR[4];

#define STAGE_B(buf, kk)                                                    \
  {                                                                         \
    _Pragma("unroll") for (int u = 0; u < 2; ++u) {                         \
      int ch = wave * 2 + u;                                                \
      size_t gi = (size_t)(n0 + ch * 16 + srow) * K + (kk) + ql8;           \
      gload16(&Bg[gi], &Bs[buf][ch * 16][0]);                               \
    }                                                                       \
  }
#define STAGE_A_DMA(buf, kk)                                                \
  {                                                                         \
    _Pragma("unroll") for (int u = 0; u < 2; ++u) {                         \
      int ch = wave * 2 + u;                                                \
      size_t gi = (size_t)(m0 + ch * 16 + srow) * K + (kk) + ql8;           \
      gload16((const f16*)Av + gi, &Ah[buf][ch * 16][0]);                   \
    }                                                                       \
  }
#define ISSUE_A(kk)                                                         \
  {                                                                         \
    const float* Af = (const float*)Av;                                     \
    _Pragma("unroll") for (int p = 0; p < 2; ++p) {                         \
      int off = p * 2048 + tid * 8;                                         \
      int r = off >> 5, cc = off & 31;                                      \
      size_t gi = (size_t)(m0 + r) * K + (kk) + cc;                         \
      aR[p * 2] = *(const floatx4*)&Af[gi];                                 \
      aR[p * 2 + 1] = *(const floatx4*)&Af[gi + 4];                         \
    }                                                                       \
  }
#define WRITE_A(buf)                                                        \
  {                                                                         \
    _Pragma("unroll") for (int p = 0; p < 2; ++p) {                         \
      int off = p * 2048 + tid * 8;                                         \
      int r = off >> 5, cc = off & 31;                                      \
      f16x8 h;                                                              \
      _Pragma("unroll") for (int uu = 0; uu < 4; ++uu) {                    \
        h[uu] = (f16)aR[p * 2][uu];                                         \
        h[4 + uu] = (f16)aR[p * 2 + 1][uu];                                 \
      }                                                                     \
      *(f16x8*)&Ah[buf][r][cc] = h;                                         \
    }                                                                       \
  }

  STAGE_B(0, 0);
  if constexpr (MODE == 1) {
    ISSUE_A(0);
    WRITE_A(0);
  } else {
    STAGE_A_DMA(0, 0);
  }
  __syncthreads();

  int nk = K / 32;
  int cur = 0;
  for (int t = 0; t < nk; ++t) {
    int kn = (t + 1) * 32;
    bool has_next = (t + 1 < nk);
    if (has_next) {
      STAGE_B(cur ^ 1, kn);
      if constexpr (MODE == 1) {
        ISSUE_A(kn);
      } else {
        STAGE_A_DMA(cur ^ 1, kn);
      }
    }

    f16x8 ah[4], bh[4];
#pragma unroll
    for (int i = 0; i < 4; ++i) {
      if constexpr (MODE == 1)
        ah[i] = *(const f16x8*)&Ah[cur][wrow + i * 16 + c][quad * 8];
      else
        ah[i] = *(const f16x8*)&Ah[cur][wrow + i * 16 + c][(quad ^ rswz) * 8];
    }
#pragma unroll
    for (int j = 0; j < 4; ++j)
      bh[j] = *(const f16x8*)&Bs[cur][wcol + j * 16 + c][(quad ^ rswz) * 8];
#pragma unroll
    for (int i = 0; i < 4; ++i)
#pragma unroll
      for (int j = 0; j < 4; ++j)
        acc[i][j] = MFMA_F16(ah[i], bh[j], acc[i][j]);

    if (has_next) {
      if constexpr (MODE == 1) WRITE_A(cur ^ 1);
      __syncthreads();
      cur ^= 1;
    }
  }
#undef STAGE_B
#undef STAGE_A_DMA
#undef ISSUE_A
#undef WRITE_A

#pragma unroll
  for (int i = 0; i < 4; ++i) {
#pragma unroll
    for (int j = 0; j < 4; ++j) {
      int col = n0 + wcol + j * 16 + c;
      float bvv = bias[col];
#pragma unroll
      for (int r = 0; r < 4; ++r) {
        int row = m0 + wrow + i * 16 + quad * 4 + r;
        float v = acc[i][j][r] + bvv;
        if constexpr (MODE == 0) {
          ((float*)Cq)[(size_t)row * N + col] = v;
        } else {
          int which = col >> 10;          // 0=Q,1=K,2=V (wave-uniform)
          int h = (col >> 6) & 15;
          int d = col & 63;
          int b = row >> 11;
          int s = row & 2047;
          if (which == 0) {
            ((bf16*)Cq)[((size_t)(b * 2048 + s)) * 1024 + h * 64 + d] = (bf16)v;
          } else if (which == 1) {
            Ck[((size_t)(b * 16 + h) * 2048 + s) * 64 + d] = (bf16)v;
          } else {
            Cv[((size_t)(b * 16 + h) * 64 + d) * 2048 + s] = (bf16)v;
          }
        }
      }
    }
  }
}

// ---------------------------------------------------------------------------
// Fused MFMA flash attention (R21 = verified R20 + PV upgraded K=8 -> K=16).
// PV's B-operand needs 8 keys/lane (k = hi*8+i); each lane's S^T reg-group
// holds 4 (keys 16u+4hi+j). The missing 4 live in the opposite 32-lane half
// (same l31) -> T12 permlane32_swap: swap(pk[2u].d0, pk[2u+1].d0) yields
// (b8.d0, b8.d2); d1-pair yields (b8.d1, b8.d3). PV: 16 MFMA(K=8) ->
// 8 MFMA(K=16) (halves PV matrix-pipe cycles); Vts reads 16 b64 -> 8 b128
// (same row/col pattern as the proven QK^T Ks read; [72]-pad is 16B-aligned:
// 144 = 16*9). Everything else identical to R20 (T5 setprio, exp2-fold,
// 32x32 QK^T, ping-pong phases, in-register P, O stored fp16).
// ---------------------------------------------------------------------------
__global__ __launch_bounds__(256) void attn_fused(
    bf16* QO, const bf16* __restrict__ Kg, const bf16* __restrict__ Vg,
    const void* __restrict__ mask) {
  __shared__ __align__(16) bf16 Ks[64][72];   // [key][d]
  __shared__ __align__(16) bf16 Vts[64][72];  // [d][key]
  __shared__ __align__(16) float abuf_all[2048];  // mv ? -12*log2e : -1e30

  const int i64 = detect_i64(mask);

  int tid = threadIdx.x;
  int wave = tid >> 6, lane = tid & 63;
  int l31 = lane & 31, hi = lane >> 5;

  // T1: XCD-chunked remap; consecutive new ids share bh -> K/V L2 reuse.
  int nwg = gridDim.x * gridDim.y;  // 1024
  int bid = blockIdx.x + gridDim.x * blockIdx.y;
  int nb = xcd_swizzle(bid, nwg);
  int qt = nb & 15, bh = nb >> 4;

  int b = bh >> 4, h = bh & 15;
  int q0 = qt * 128;
  bf16* Qp = QO + (size_t)b * 2048 * 1024 + h * 64;  // row stride 1024
  const bf16* Kp = Kg + (size_t)bh * 2048 * 64;      // [s][d]
  const bf16* Vp = Vg + (size_t)bh * 64 * 2048;      // [d][s] (transposed)

  // mask table for all 2048 keys of batch b (log2e units; once, read-only)
#pragma unroll
  for (int i = 0; i < 8; ++i) {
    int key = tid * 8 + i;
    int idx = b * 2048 + key;
    int mv = i64 ? (int)((const long long*)mask)[idx]
                 : ((const int*)mask)[idx];
    abuf_all[key] = mv ? -17.3123404907f : -1e30f;
  }

  // Q frags (B-operand of 32x32x16 QK^T): col q = l31, k = hi*8+i per dstep.
  int qrow = q0 + wave * 32 + l31;
  bf16x8 qf[4];
#pragma unroll
  for (int ds = 0; ds < 4; ++ds)
    qf[ds] = *(const bf16x8*)&Qp[(size_t)qrow * 1024 + ds * 16 + hi * 8];

  floatx16 o[2];
#pragma unroll
  for (int dt = 0; dt < 2; ++dt)
#pragma unroll
    for (int i = 0; i < 16; ++i) o[dt][i] = 0.f;
  float lacc = 0.f;

  // prologue: stage K_0
#pragma unroll
  for (int p = 0; p < 2; ++p) {
    int off = p * 2048 + tid * 8;
    int r = off >> 6, cc = off & 63;
    *(bf16x8*)&Ks[r][cc] = *(const bf16x8*)&Kp[(size_t)r * 64 + cc];
  }
  __syncthreads();  // Ks_0 + abuf_all visible

  bf16x4 pk[8];  // P^T frags: pk[t2*4+s] = keys t2*32 + 8s + 4hi + j

  for (int kt = 0; kt < 32; ++kt) {
    int k0 = kt * 64;

    // ---- phase A: issue V_t; QK^T both tiles; softmax->pk; write V_t ----
    bf16x8 vstage[2];
#pragma unroll
    for (int p = 0; p < 2; ++p) {
      int off = p * 2048 + tid * 8;
      int r = off >> 6, cc = off & 63;
      vstage[p] = *(const bf16x8*)&Vp[(size_t)r * 2048 + k0 + cc];
    }

#pragma unroll
    for (int t2 = 0; t2 < 2; ++t2) {
      floatx16 sr;
#pragma unroll
      for (int i = 0; i < 16; ++i) sr[i] = 0.f;
      // T5: favor this wave while it owns the matrix pipe
      __builtin_amdgcn_s_setprio(1);
#pragma unroll
      for (int ds = 0; ds < 4; ++ds) {
        bf16x8 ak = *(const bf16x8*)&Ks[t2 * 32 + l31][ds * 16 + hi * 8];
        sr = MFMA32_BF16(ak, qf[ds], sr);
      }
      __builtin_amdgcn_s_setprio(0);
      // softmax in-register; reg group 4s..4s+3 -> keys t2*32+8s+4hi+j
#pragma unroll
      for (int s = 0; s < 4; ++s) {
        floatx4 am = *(const floatx4*)&abuf_all[k0 + t2 * 32 + s * 8 + hi * 4];
        bf16x4 p4;
#pragma unroll
        for (int j = 0; j < 4; ++j) {
          // exp(x/8 - 12) == exp2(x*0.125*log2e - 12*log2e)
          float pv = fast_exp2(fmaf(sr[s * 4 + j], 0.1803368801f, am[j]));
          lacc += pv;
          p4[j] = (bf16)pv;
        }
        pk[t2 * 4 + s] = p4;
      }
    }

    // write V_t (vstage vmcnt hidden under QK^T/softmax)
#pragma unroll
    for (int p = 0; p < 2; ++p) {
      int off = p * 2048 + tid * 8;
      int r = off >> 6, cc = off & 63;
      *(bf16x8*)&Vts[r][cc] = vstage[p];
    }
    __syncthreads();  // V_t visible; Ks free for overwrite

    // ---- phase B: issue K_{t+1}; PV (K=16); write K_{t+1} ----
    bf16x8 kstage[2];
    bool more = (kt + 1) < 32;
    int kn = k0 + 64;
    if (more) {
#pragma unroll
      for (int p = 0; p < 2; ++p) {
        int off = p * 2048 + tid * 8;
        int r = off >> 6, cc = off & 63;
        kstage[p] = *(const bf16x8*)&Kp[(size_t)(kn + r) * 64 + cc];
      }
    }

    // O^T += V^T @ P^T with K=16: per 16-key slice u, build the B-frag
    // b8[i] = P[key 16u+8hi+i][q=l31] from pk[2u], pk[2u+1] via half_swap.
    __builtin_amdgcn_s_setprio(1);
#pragma unroll
    for (int u = 0; u < 4; ++u) {
      uintx2 pa, pb;
      __builtin_memcpy(&pa, &pk[2 * u], 8);
      __builtin_memcpy(&pb, &pk[2 * u + 1], 8);
      unsigned bw0, bw1, bw2, bw3;
      half_swap(pa[0], pb[0], hi, bw0, bw2);
      half_swap(pa[1], pb[1], hi, bw1, bw3);
      unsigned bw[4] = {bw0, bw1, bw2, bw3};
      bf16x8 b8;
      __builtin_memcpy(&b8, bw, 16);
#pragma unroll
      for (int dt = 0; dt < 2; ++dt) {
        bf16x8 av = *(const bf16x8*)&Vts[dt * 32 + l31][u * 16 + hi * 8];
        o[dt] = MFMA32_BF16(av, b8, o[dt]);
      }
    }
    __builtin_amdgcn_s_setprio(0);

    if (more) {
#pragma unroll
      for (int p = 0; p < 2; ++p) {
        int off = p * 2048 + tid * 8;
        int r = off >> 6, cc = off & 63;
        *(bf16x8*)&Ks[r][cc] = kstage[p];
      }
      __syncthreads();  // K_{t+1} visible; Vts free
    }
  }

  // l(q) = own half (this hi's 32 keys/kt) + partner half
  lacc += __shfl_xor(lacc, 32, 64);
  float inv = 1.0f / fmaxf(lacc, 1e-30f);

  // O^T C/D: col q = l31, row d_local = (reg&3)+8*(reg>>2)+4*hi (+32*dt).
  // Store fp16, groups of 4 consecutive d.
#pragma unroll
  for (int dt = 0; dt < 2; ++dt) {
#pragma unroll
    for (int t = 0; t < 4; ++t) {
      f16x4 out;
#pragma unroll
      for (int j = 0; j < 4; ++j) out[j] = (f16)(o[dt][t * 4 + j] * inv);
      int d0 = dt * 32 + t * 8 + hi * 4;
      *(f16x4*)((f16*)&Qp[(size_t)qrow * 1024] + d0) = out;
    }
  }
}

// ---------------------------------------------------------------------------
extern "C" void kernel_launch(void* const* d_in, const int* in_sizes, int n_in,
                              void* d_out, int out_size, void* d_ws, size_t ws_size,
                              hipStream_t stream) {
  (void)in_sizes; (void)n_in; (void)out_size;
  const float* hs    = (const float*)d_in[0];  // [4,2048,1024] fp32
  const float* qkv_w = (const float*)d_in[1];  // [1024,3072] fp32
  const float* qkv_b = (const float*)d_in[2];  // [3072] fp32
  const float* wo_w  = (const float*)d_in[3];  // [1024,1024] fp32
  const float* wo_b  = (const float*)d_in[4];  // [1024] fp32
  const void*  mask  = d_in[5];                // [4,2048] int32/64 (detected)

  if (ws_size < 33554432) return;  // R3-verified: ws >= 32 MiB

  // ws (32 MiB): [0:16MiB) K bf16, later O copy; [16MiB:+6MiB) Wqkv fp16;
  // [+22MiB:+2MiB) Wo fp16. d_out (32 MiB fp32): [0:16MiB) Q->O; [16:32MiB)
  // V^T bf16 (both dead before the fp32 proj store).
  bf16* kbuf = (bf16*)d_ws;
  f16*  wq   = (f16*)((char*)d_ws + 16777216);            // 3072*1024 fp16
  f16*  wo   = (f16*)((char*)d_ws + 16777216 + 6291456);  // 1024*1024 fp16
  bf16* vbuf = (bf16*)d_out + (size_t)8388608;
  f16*  obuf = (f16*)d_ws;

  // 0. pre-convert + pre-transpose weights to fp16 (once)
  wsplit<<<dim3(96, 32), dim3(32, 8), 0, stream>>>(qkv_w, wq, 1024, 3072);
  wsplit<<<dim3(32, 32), dim3(32, 8), 0, stream>>>(wo_w, wo, 1024, 1024);

  // 1. QKV projection: Q -> d_out[0:16MiB), K -> ws, V^T -> d_out[16:32MiB)
  gemm<1><<<dim3(24, 64), 256, 0, stream>>>(
      hs, wq, qkv_b, d_out, kbuf, vbuf, 8192, 3072, 1024);

  // 2. fused attention, in-place on d_out[0:16MiB) (O written as fp16)
  attn_fused<<<dim3(16, 64), 256, 0, stream>>>(
      (bf16*)d_out, kbuf, vbuf, mask);

  // 3. O -> ws[0:16MiB) (K dead)
  (void)hipMemcpyAsync(d_ws, d_out, (size_t)16777216, hipMemcpyDeviceToDevice,
                       stream);

  // 4. output projection: fp16 O @ Wo -> fp32 d_out
  gemm<0><<<dim3(8, 64), 256, 0, stream>>>(
      obuf, wo, wo_b, d_out, nullptr, nullptr, 8192, 1024, 1024);
}